// Round 1
// baseline (83.353 us; speedup 1.0000x reference)
//
#include <hip/hip_runtime.h>

// SpanIndexEncoder: out[t,f] = sum_n [start_n <= t <= end_n] * embed[n,f]
// N=1024 nodes, T=2048 tokens, F=128 features, all fp32.
//
// Strategy: per-tile difference array + local prefix sum.
// For token tile [t0, t1]: clamp each span to the tile; a node whose span
// covers t0 contributes at local row 0, so the tile-local cumsum needs no
// carry-in from earlier tokens. Fully parallel across tiles, one kernel.

#define T_TOKENS 2048
#define N_NODES  1024
#define F        128
#define TB       8            // tokens per block/tile
#define SLICES   4            // node-parallel slices; block = SLICES*F = 512 thr

__global__ __launch_bounds__(SLICES * F)
void span_encode_kernel(const int* __restrict__ starts,
                        const int* __restrict__ ends,
                        const float* __restrict__ embed,
                        float* __restrict__ out)
{
    __shared__ int   s_start[N_NODES];
    __shared__ int   s_end[N_NODES];
    // per-slice difference array; row TB is the trash row for (b+1) == t1+1
    __shared__ float diff[SLICES][TB + 1][F];

    const int tid = threadIdx.x;
    const int t0  = blockIdx.x * TB;
    const int t1  = t0 + TB - 1;

    // stage span bounds (coalesced, L2-resident)
    for (int i = tid; i < N_NODES; i += SLICES * F) {
        s_start[i] = starts[i];
        s_end[i]   = ends[i];
    }
    // zero the diff arrays (harness poisons LDS-free state; LDS starts undefined)
    for (int i = tid; i < SLICES * (TB + 1) * F; i += SLICES * F) {
        ((float*)diff)[i] = 0.0f;
    }
    __syncthreads();

    const int slice  = tid >> 7;        // 0..SLICES-1 (wave-uniform)
    const int f      = tid & (F - 1);   // 0..127
    const int n_base = slice * (N_NODES / SLICES);

    // Node loop: n is wave-uniform -> no divergence; embed row load is
    // 64-lane coalesced; diff RMW is 2-way bank aliased (free on gfx950).
    for (int i = 0; i < N_NODES / SLICES; ++i) {
        const int n = n_base + i;
        const int s = s_start[n];
        const int e = s_end[n];
        const int a = max(s, t0);
        const int b = min(e, t1);
        if (a <= b) {                       // also skips invalid spans (s > e)
            const float v = embed[n * F + f];
            diff[slice][a - t0][f]     += v;
            diff[slice][b + 1 - t0][f] -= v;
        }
    }
    __syncthreads();

    // tile-local prefix sum over TB rows, summing the 4 slices; write out.
    if (tid < F) {
        float acc = 0.0f;
        for (int i = 0; i < TB; ++i) {
            acc += diff[0][i][tid] + diff[1][i][tid]
                 + diff[2][i][tid] + diff[3][i][tid];
            out[(t0 + i) * F + tid] = acc;   // coalesced 512B row store
        }
    }
}

extern "C" void kernel_launch(void* const* d_in, const int* in_sizes, int n_in,
                              void* d_out, int out_size, void* d_ws, size_t ws_size,
                              hipStream_t stream) {
    const int*   starts = (const int*)d_in[0];
    const int*   ends   = (const int*)d_in[1];
    const float* embed  = (const float*)d_in[2];
    float*       out    = (float*)d_out;

    span_encode_kernel<<<T_TOKENS / TB, SLICES * F, 0, stream>>>(starts, ends, embed, out);
}

// Round 2
// 72.899 us; speedup vs baseline: 1.1434x; 1.1434x over previous
//
#include <hip/hip_runtime.h>

// SpanIndexEncoder: out[t,f] = sum_n [start_n <= t <= end_n] * embed[n,f]
// N=1024 nodes, T=2048 tokens, F=128 features, all fp32.
//
// Two-phase per-tile approach (8 tokens/block, 256 blocks):
//  Phase 1: 512 threads test all 1024 spans against the tile, compact the
//           ~170 intersecting ones into LDS (packed n|a|b), one LDS atomic
//           per hit.
//  Phase 2: 4 node-slices x 128 features walk the compacted list with pure
//           register accumulators (8 branchless cndmask-adds per entry) --
//           no LDS read-modify-write dependency chains. Cross-slice 4-way
//           reduction via LDS, coalesced 512B row stores.

#define T_TOKENS 2048
#define N_NODES  1024
#define F        128
#define TB       8
#define SLICES   4
#define NTHREADS (SLICES * F)   // 512

__global__ __launch_bounds__(NTHREADS)
void span_encode_kernel(const int* __restrict__ starts,
                        const int* __restrict__ ends,
                        const float* __restrict__ embed,
                        float* __restrict__ out)
{
    __shared__ int   s_count;
    __shared__ int   s_entries[N_NODES];
    __shared__ float red[SLICES][TB][F];   // 16 KB

    const int tid = threadIdx.x;
    const int t0  = blockIdx.x * TB;
    const int t1  = t0 + TB - 1;

    if (tid == 0) s_count = 0;
    __syncthreads();

    // Phase 1: test + compact. starts/ends loads are coalesced, L2-resident.
    #pragma unroll
    for (int k = 0; k < N_NODES / NTHREADS; ++k) {
        const int n = tid + k * NTHREADS;
        const int s = starts[n];
        const int e = ends[n];
        const int A = max(s, t0);
        const int B = min(e, t1);
        if (A <= B) {   // also rejects invalid spans (s > e)
            const int entry = n | ((A - t0) << 10) | ((B - t0) << 13);
            const int idx   = atomicAdd(&s_count, 1);
            s_entries[idx]  = entry;
        }
    }
    __syncthreads();
    const int cnt = s_count;

    const int slice = tid >> 7;        // 0..3
    const int f     = tid & (F - 1);   // 0..127

    float acc[TB];
    #pragma unroll
    for (int r = 0; r < TB; ++r) acc[r] = 0.0f;

    // Phase 2: ~cnt/4 entries per slice (~43 avg). Entry read is an LDS
    // broadcast; embed row load is 64-lane coalesced and L2-resident; the
    // 8 accumulators pipeline freely (no cross-iteration address hazards).
    for (int i = slice; i < cnt; i += SLICES) {
        const int   ent = s_entries[i];
        const int   n   = ent & (N_NODES - 1);
        const int   a   = (ent >> 10) & 7;
        const int   b   = (ent >> 13) & 7;
        const float v   = embed[n * F + f];
        #pragma unroll
        for (int r = 0; r < TB; ++r) {
            acc[r] += ((unsigned)(r - a) <= (unsigned)(b - a)) ? v : 0.0f;
        }
    }

    #pragma unroll
    for (int r = 0; r < TB; ++r) red[slice][r][f] = acc[r];
    __syncthreads();

    // 1024 outputs, 512 threads -> 2 each; consecutive tid = consecutive f
    // within a token row -> conflict-free LDS reads, coalesced stores.
    #pragma unroll
    for (int k = 0; k < TB * F / NTHREADS; ++k) {
        const int idx = tid + k * NTHREADS;
        const int r   = idx >> 7;
        const int ff  = idx & (F - 1);
        out[(t0 + r) * F + ff] = red[0][r][ff] + red[1][r][ff]
                               + red[2][r][ff] + red[3][r][ff];
    }
}

extern "C" void kernel_launch(void* const* d_in, const int* in_sizes, int n_in,
                              void* d_out, int out_size, void* d_ws, size_t ws_size,
                              hipStream_t stream) {
    const int*   starts = (const int*)d_in[0];
    const int*   ends   = (const int*)d_in[1];
    const float* embed  = (const float*)d_in[2];
    float*       out    = (float*)d_out;

    span_encode_kernel<<<T_TOKENS / TB, NTHREADS, 0, stream>>>(starts, ends, embed, out);
}